// Round 1
// baseline (3438.548 us; speedup 1.0000x reference)
//
#include <hip/hip_runtime.h>

#define NN 50000
#define NE 800000
#define F 128

// ---------------------------------------------------------------------------
// dtype probe: if edge_index is int64 (little-endian, values < 50000), every
// odd 32-bit word in the first 2*NE words is the zero high-half of a src
// qword. If int32, those words are random node ids -> count nonzeros.
// ---------------------------------------------------------------------------
__global__ void k_detect(const unsigned int* __restrict__ w, int* __restrict__ nz) {
    int i = blockIdx.x * blockDim.x + threadIdx.x;
    if (i < NE) {
        if (w[2 * i + 1] != 0u) atomicAdd(nz, 1);
    }
}

// normalize edge_index -> int32 src/dst, and histogram in-degree (cnt[dst]++)
__global__ void k_convert(const void* __restrict__ ei, const int* __restrict__ nz,
                          int* __restrict__ src, int* __restrict__ dst,
                          int* __restrict__ cnt) {
    int e = blockIdx.x * blockDim.x + threadIdx.x;
    if (e >= NE) return;
    int s, d;
    if (*nz == 0) {  // int64 layout
        const long long* p = (const long long*)ei;
        s = (int)p[e];
        d = (int)p[NE + e];
    } else {         // int32 layout
        const int* p = (const int*)ei;
        s = p[e];
        d = p[NE + e];
    }
    src[e] = s;
    dst[e] = d;
    atomicAdd(&cnt[d], 1);
}

__global__ void k_inv(const int* __restrict__ cnt, float* __restrict__ inv) {
    int i = blockIdx.x * blockDim.x + threadIdx.x;
    if (i < NN) inv[i] = 1.0f / (float)max(cnt[i], 1);
}

// scatter-add: agg[dst[e]] += xin[src[e]]  (float4 per thread, fp32 atomics)
__global__ void k_scatter(const float* __restrict__ xin, const int* __restrict__ src,
                          const int* __restrict__ dst, float* __restrict__ agg) {
    int t = blockIdx.x * blockDim.x + threadIdx.x;  // NE*32 threads
    int e = t >> 5;
    if (e >= NE) return;
    int c = (t & 31) << 2;
    int s = src[e], d = dst[e];
    float4 v = *(const float4*)(xin + (size_t)s * F + c);
    float* o = agg + (size_t)d * F + c;
    atomicAdd(o + 0, v.x);
    atomicAdd(o + 1, v.y);
    atomicAdd(o + 2, v.z);
    atomicAdd(o + 3, v.w);
}

// ---------------------------------------------------------------------------
// C[r][:] = act( (A1[r]*inv[r]) @ WA + A2[r] @ WB + bias )   (K=128 each)
// fp32 vector GEMM, 32-row tile per block, each thread: 4 rows x 4 cols.
// ---------------------------------------------------------------------------
__launch_bounds__(256)
__global__ void k_gemm_conv(const float* __restrict__ A1, const float* __restrict__ inv,
                            const float* __restrict__ A2,
                            const float* __restrict__ WA, const float* __restrict__ WB,
                            const float* __restrict__ bias, float* __restrict__ C,
                            int relu) {
    __shared__ float sA[32][256];  // [row][k]: k<128 = A1*inv, k>=128 = A2
    int row0 = blockIdx.x * 32;
    int tid = threadIdx.x;

    for (int i = tid; i < 32 * 32; i += 256) {
        int r = i >> 5, c4 = (i & 31) << 2;
        int gr = row0 + r;
        float4 v = make_float4(0.f, 0.f, 0.f, 0.f);
        float s = 0.f;
        if (gr < NN) {
            v = *(const float4*)(A1 + (size_t)gr * F + c4);
            s = inv[gr];
        }
        sA[r][c4 + 0] = v.x * s;
        sA[r][c4 + 1] = v.y * s;
        sA[r][c4 + 2] = v.z * s;
        sA[r][c4 + 3] = v.w * s;
    }
    for (int i = tid; i < 32 * 32; i += 256) {
        int r = i >> 5, c4 = (i & 31) << 2;
        int gr = row0 + r;
        float4 v = make_float4(0.f, 0.f, 0.f, 0.f);
        if (gr < NN) v = *(const float4*)(A2 + (size_t)gr * F + c4);
        sA[r][128 + c4 + 0] = v.x;
        sA[r][128 + c4 + 1] = v.y;
        sA[r][128 + c4 + 2] = v.z;
        sA[r][128 + c4 + 3] = v.w;
    }
    __syncthreads();

    int tr = tid >> 5;          // 0..7 -> rows tr*4 .. tr*4+3
    int tc = (tid & 31) << 2;   // cols tc .. tc+3
    float acc[4][4] = {};

#pragma unroll 4
    for (int k = 0; k < 256; ++k) {
        const float* Wrow = (k < 128) ? (WA + (size_t)k * F)
                                      : (WB + (size_t)(k - 128) * F);
        float4 w = *(const float4*)(Wrow + tc);
        float a0 = sA[tr * 4 + 0][k];
        float a1 = sA[tr * 4 + 1][k];
        float a2 = sA[tr * 4 + 2][k];
        float a3 = sA[tr * 4 + 3][k];
        acc[0][0] += a0 * w.x; acc[0][1] += a0 * w.y; acc[0][2] += a0 * w.z; acc[0][3] += a0 * w.w;
        acc[1][0] += a1 * w.x; acc[1][1] += a1 * w.y; acc[1][2] += a1 * w.z; acc[1][3] += a1 * w.w;
        acc[2][0] += a2 * w.x; acc[2][1] += a2 * w.y; acc[2][2] += a2 * w.z; acc[2][3] += a2 * w.w;
        acc[3][0] += a3 * w.x; acc[3][1] += a3 * w.y; acc[3][2] += a3 * w.z; acc[3][3] += a3 * w.w;
    }

    float4 b = *(const float4*)(bias + tc);
#pragma unroll
    for (int i = 0; i < 4; ++i) {
        int gr = row0 + tr * 4 + i;
        if (gr >= NN) continue;
        float4 o;
        o.x = acc[i][0] + b.x;
        o.y = acc[i][1] + b.y;
        o.z = acc[i][2] + b.z;
        o.w = acc[i][3] + b.w;
        if (relu) {
            o.x = fmaxf(o.x, 0.f); o.y = fmaxf(o.y, 0.f);
            o.z = fmaxf(o.z, 0.f); o.w = fmaxf(o.w, 0.f);
        }
        *(float4*)(C + (size_t)gr * F + tc) = o;
    }
}

// ---------------------------------------------------------------------------
// C1 = A @ W1, C2 = A @ W2  (K=128, no bias/act) -> Gs, Gd precompute
// ---------------------------------------------------------------------------
__launch_bounds__(256)
__global__ void k_gemm_dual(const float* __restrict__ A,
                            const float* __restrict__ W1, const float* __restrict__ W2,
                            float* __restrict__ C1, float* __restrict__ C2) {
    __shared__ float sA[32][128];
    int row0 = blockIdx.x * 32;
    int tid = threadIdx.x;

    for (int i = tid; i < 32 * 32; i += 256) {
        int r = i >> 5, c4 = (i & 31) << 2;
        int gr = row0 + r;
        float4 v = make_float4(0.f, 0.f, 0.f, 0.f);
        if (gr < NN) v = *(const float4*)(A + (size_t)gr * F + c4);
        sA[r][c4 + 0] = v.x;
        sA[r][c4 + 1] = v.y;
        sA[r][c4 + 2] = v.z;
        sA[r][c4 + 3] = v.w;
    }
    __syncthreads();

    int tr = tid >> 5;
    int tc = (tid & 31) << 2;
    float acc1[4][4] = {};
    float acc2[4][4] = {};

#pragma unroll 4
    for (int k = 0; k < 128; ++k) {
        float4 w1 = *(const float4*)(W1 + (size_t)k * F + tc);
        float4 w2 = *(const float4*)(W2 + (size_t)k * F + tc);
        float a0 = sA[tr * 4 + 0][k];
        float a1 = sA[tr * 4 + 1][k];
        float a2 = sA[tr * 4 + 2][k];
        float a3 = sA[tr * 4 + 3][k];
        acc1[0][0] += a0 * w1.x; acc1[0][1] += a0 * w1.y; acc1[0][2] += a0 * w1.z; acc1[0][3] += a0 * w1.w;
        acc1[1][0] += a1 * w1.x; acc1[1][1] += a1 * w1.y; acc1[1][2] += a1 * w1.z; acc1[1][3] += a1 * w1.w;
        acc1[2][0] += a2 * w1.x; acc1[2][1] += a2 * w1.y; acc1[2][2] += a2 * w1.z; acc1[2][3] += a2 * w1.w;
        acc1[3][0] += a3 * w1.x; acc1[3][1] += a3 * w1.y; acc1[3][2] += a3 * w1.z; acc1[3][3] += a3 * w1.w;
        acc2[0][0] += a0 * w2.x; acc2[0][1] += a0 * w2.y; acc2[0][2] += a0 * w2.z; acc2[0][3] += a0 * w2.w;
        acc2[1][0] += a1 * w2.x; acc2[1][1] += a1 * w2.y; acc2[1][2] += a1 * w2.z; acc2[1][3] += a1 * w2.w;
        acc2[2][0] += a2 * w2.x; acc2[2][1] += a2 * w2.y; acc2[2][2] += a2 * w2.z; acc2[2][3] += a2 * w2.w;
        acc2[3][0] += a3 * w2.x; acc2[3][1] += a3 * w2.y; acc2[3][2] += a3 * w2.z; acc2[3][3] += a3 * w2.w;
    }

#pragma unroll
    for (int i = 0; i < 4; ++i) {
        int gr = row0 + tr * 4 + i;
        if (gr >= NN) continue;
        float4 o1 = make_float4(acc1[i][0], acc1[i][1], acc1[i][2], acc1[i][3]);
        float4 o2 = make_float4(acc2[i][0], acc2[i][1], acc2[i][2], acc2[i][3]);
        *(float4*)(C1 + (size_t)gr * F + tc) = o1;
        *(float4*)(C2 + (size_t)gr * F + tc) = o2;
    }
}

// ---------------------------------------------------------------------------
// edge classifier: one wave per edge.
// out[e] = relu(Gs[src]+Gd[dst]+ea@Wc1e+bc1) . Wc2 + bc2
// ---------------------------------------------------------------------------
__launch_bounds__(256)
__global__ void k_edge(const float* __restrict__ Gs, const float* __restrict__ Gd,
                       const float* __restrict__ ea, const int* __restrict__ src,
                       const int* __restrict__ dst, const float* __restrict__ Wc1e,
                       const float* __restrict__ bc1, const float* __restrict__ Wc2,
                       const float* __restrict__ bc2, float* __restrict__ out) {
    int gt = blockIdx.x * blockDim.x + threadIdx.x;
    int e = gt >> 6;
    int lane = threadIdx.x & 63;
    if (e >= NE) return;
    int s = src[e], d = dst[e];
    int c = lane * 2;

    float2 gs = *(const float2*)(Gs + (size_t)s * F + c);
    float2 gd = *(const float2*)(Gd + (size_t)d * F + c);
    float e0 = ea[(size_t)e * 3 + 0];
    float e1 = ea[(size_t)e * 3 + 1];
    float e2 = ea[(size_t)e * 3 + 2];
    float2 w0 = *(const float2*)(Wc1e + 0 * F + c);
    float2 w1 = *(const float2*)(Wc1e + 1 * F + c);
    float2 w2 = *(const float2*)(Wc1e + 2 * F + c);
    float2 b  = *(const float2*)(bc1 + c);

    float h0 = gs.x + gd.x + e0 * w0.x + e1 * w1.x + e2 * w2.x + b.x;
    float h1 = gs.y + gd.y + e0 * w0.y + e1 * w1.y + e2 * w2.y + b.y;
    h0 = fmaxf(h0, 0.f);
    h1 = fmaxf(h1, 0.f);

    float2 wc = *(const float2*)(Wc2 + c);
    float p = h0 * wc.x + h1 * wc.y;
#pragma unroll
    for (int off = 32; off > 0; off >>= 1) p += __shfl_down(p, off, 64);
    if (lane == 0) out[e] = p + bc2[0];
}

// ---------------------------------------------------------------------------
extern "C" void kernel_launch(void* const* d_in, const int* in_sizes, int n_in,
                              void* d_out, int out_size, void* d_ws, size_t ws_size,
                              hipStream_t stream) {
    const float* x    = (const float*)d_in[0];
    const void*  ei   = d_in[1];
    const float* ea   = (const float*)d_in[2];
    const float* W1l  = (const float*)d_in[3];
    const float* b1l  = (const float*)d_in[4];
    const float* W1r  = (const float*)d_in[5];
    const float* W2l  = (const float*)d_in[6];
    const float* b2l  = (const float*)d_in[7];
    const float* W2r  = (const float*)d_in[8];
    const float* Wc1  = (const float*)d_in[9];
    const float* bc1  = (const float*)d_in[10];
    const float* Wc2  = (const float*)d_in[11];
    const float* bc2  = (const float*)d_in[12];
    float* out = (float*)d_out;

    char* w = (char*)d_ws;
    int* flag = (int*)w;            w += 256;
    int* src  = (int*)w;            w += (size_t)NE * 4;
    int* dst  = (int*)w;            w += (size_t)NE * 4;
    int* cnt  = (int*)w;            w += (size_t)NN * 4;
    float* inv = (float*)w;         w += (size_t)NN * 4;
    w = (char*)(((size_t)w + 255) & ~(size_t)255);
    float* B0 = (float*)w;          w += (size_t)NN * F * 4;  // agg1, agg2, Gs
    float* B1 = (float*)w;          w += (size_t)NN * F * 4;  // h1, Gd
    float* B2 = (float*)w;          w += (size_t)NN * F * 4;  // h2

    hipMemsetAsync(flag, 0, 4, stream);
    hipMemsetAsync(cnt, 0, (size_t)NN * 4, stream);
    hipMemsetAsync(B0, 0, (size_t)NN * F * 4, stream);

    k_detect<<<(NE + 255) / 256, 256, 0, stream>>>((const unsigned int*)ei, flag);
    k_convert<<<(NE + 255) / 256, 256, 0, stream>>>(ei, flag, src, dst, cnt);
    k_inv<<<(NN + 255) / 256, 256, 0, stream>>>(cnt, inv);

    // conv1
    k_scatter<<<(NE * 32) / 256, 256, 0, stream>>>(x, src, dst, B0);
    int gblocks = (NN + 31) / 32;
    k_gemm_conv<<<gblocks, 256, 0, stream>>>(B0, inv, x, W1l, W1r, b1l, B1, 1);

    // conv2
    hipMemsetAsync(B0, 0, (size_t)NN * F * 4, stream);
    k_scatter<<<(NE * 32) / 256, 256, 0, stream>>>(B1, src, dst, B0);
    k_gemm_conv<<<gblocks, 256, 0, stream>>>(B0, inv, B1, W2l, W2r, b2l, B2, 0);

    // classifier node-side precompute: Gs = h2 @ Wc1[0:128], Gd = h2 @ Wc1[128:256]
    k_gemm_dual<<<gblocks, 256, 0, stream>>>(B2, Wc1, Wc1 + 128 * F, B0, B1);

    // edge pass: one wave per edge
    k_edge<<<(NE * 64) / 256, 256, 0, stream>>>(B0, B1, ea, src, dst,
                                                Wc1 + 256 * F, bc1, Wc2, bc2, out);
}

// Round 2
// 793.279 us; speedup vs baseline: 4.3346x; 4.3346x over previous
//
#include <hip/hip_runtime.h>

#define NN 50000
#define NE 800000
#define F 128
#define NBLK ((NN + 255) / 256)   // 196 scan blocks

// ---------------------------------------------------------------------------
// dtype probe: if edge_index is int64 (little-endian, values < 50000), every
// odd 32-bit word is the zero high-half. If int32, those are random node ids.
// ---------------------------------------------------------------------------
__global__ void k_detect(const unsigned int* __restrict__ w, int* __restrict__ nz) {
    int i = blockIdx.x * blockDim.x + threadIdx.x;
    if (i < NE) {
        if (w[2 * i + 1] != 0u) atomicAdd(nz, 1);
    }
}

// normalize edge_index -> int32 src/dst, and histogram in-degree (cnt[dst]++)
__global__ void k_convert(const void* __restrict__ ei, const int* __restrict__ nz,
                          int* __restrict__ src, int* __restrict__ dst,
                          int* __restrict__ cnt) {
    int e = blockIdx.x * blockDim.x + threadIdx.x;
    if (e >= NE) return;
    int s, d;
    if (*nz == 0) {  // int64 layout
        const long long* p = (const long long*)ei;
        s = (int)p[e];
        d = (int)p[NE + e];
    } else {         // int32 layout
        const int* p = (const int*)ei;
        s = p[e];
        d = p[NE + e];
    }
    src[e] = s;
    dst[e] = d;
    atomicAdd(&cnt[d], 1);
}

__global__ void k_inv(const int* __restrict__ cnt, float* __restrict__ inv) {
    int i = blockIdx.x * blockDim.x + threadIdx.x;
    if (i < NN) inv[i] = 1.0f / (float)max(cnt[i], 1);
}

// ---- exclusive scan of cnt[NN] -> rowptr[NN+1], plus a working copy fill[]
__global__ void k_bsum(const int* __restrict__ cnt, int* __restrict__ bsum) {
    __shared__ int s[256];
    int i = blockIdx.x * 256 + threadIdx.x;
    s[threadIdx.x] = (i < NN) ? cnt[i] : 0;
    __syncthreads();
    for (int st = 128; st > 0; st >>= 1) {
        if (threadIdx.x < st) s[threadIdx.x] += s[threadIdx.x + st];
        __syncthreads();
    }
    if (threadIdx.x == 0) bsum[blockIdx.x] = s[0];
}

__global__ void k_bscan(const int* __restrict__ bsum, int* __restrict__ boff) {
    int acc = 0;
    for (int b = 0; b < NBLK; ++b) { boff[b] = acc; acc += bsum[b]; }
}

__global__ void k_scan2(const int* __restrict__ cnt, const int* __restrict__ boff,
                        int* __restrict__ rowptr, int* __restrict__ fill) {
    __shared__ int s[256];
    int i = blockIdx.x * 256 + threadIdx.x;
    int v = (i < NN) ? cnt[i] : 0;
    s[threadIdx.x] = v;
    __syncthreads();
    for (int st = 1; st < 256; st <<= 1) {
        int t = (threadIdx.x >= st) ? s[threadIdx.x - st] : 0;
        __syncthreads();
        s[threadIdx.x] += t;
        __syncthreads();
    }
    int excl = s[threadIdx.x] - v + boff[blockIdx.x];
    if (i < NN) { rowptr[i] = excl; fill[i] = excl; }
    if (i == NN - 1) rowptr[NN] = excl + v;
}

// counting-sort edges by dst: ssort[pos] = src[e]
__global__ void k_perm(const int* __restrict__ src, const int* __restrict__ dst,
                       int* __restrict__ fill, int* __restrict__ ssort) {
    int e = blockIdx.x * 256 + threadIdx.x;
    if (e >= NE) return;
    int pos = atomicAdd(&fill[dst[e]], 1);
    ssort[pos] = src[e];
}

// gather-reduce: agg[n] = sum over in-neighbors of xin[src]; 32 threads/node
__launch_bounds__(256)
__global__ void k_gather(const float* __restrict__ xin, const int* __restrict__ rowptr,
                         const int* __restrict__ ssort, float* __restrict__ agg) {
    int n = blockIdx.x * 8 + (threadIdx.x >> 5);
    if (n >= NN) return;
    int c = (threadIdx.x & 31) << 2;
    int beg = rowptr[n], end = rowptr[n + 1];
    float4 acc = make_float4(0.f, 0.f, 0.f, 0.f);
    for (int j = beg; j < end; ++j) {
        int s = ssort[j];
        float4 v = *(const float4*)(xin + (size_t)s * F + c);
        acc.x += v.x; acc.y += v.y; acc.z += v.z; acc.w += v.w;
    }
    *(float4*)(agg + (size_t)n * F + c) = acc;
}

// ---------------------------------------------------------------------------
// C[r][:] = act( (A1[r]*inv[r]) @ WA + A2[r] @ WB + bias )   (K=128 each)
// ---------------------------------------------------------------------------
__launch_bounds__(256)
__global__ void k_gemm_conv(const float* __restrict__ A1, const float* __restrict__ inv,
                            const float* __restrict__ A2,
                            const float* __restrict__ WA, const float* __restrict__ WB,
                            const float* __restrict__ bias, float* __restrict__ C,
                            int relu) {
    __shared__ float sA[32][256];  // [row][k]: k<128 = A1*inv, k>=128 = A2
    int row0 = blockIdx.x * 32;
    int tid = threadIdx.x;

    for (int i = tid; i < 32 * 32; i += 256) {
        int r = i >> 5, c4 = (i & 31) << 2;
        int gr = row0 + r;
        float4 v = make_float4(0.f, 0.f, 0.f, 0.f);
        float s = 0.f;
        if (gr < NN) {
            v = *(const float4*)(A1 + (size_t)gr * F + c4);
            s = inv[gr];
        }
        sA[r][c4 + 0] = v.x * s;
        sA[r][c4 + 1] = v.y * s;
        sA[r][c4 + 2] = v.z * s;
        sA[r][c4 + 3] = v.w * s;
    }
    for (int i = tid; i < 32 * 32; i += 256) {
        int r = i >> 5, c4 = (i & 31) << 2;
        int gr = row0 + r;
        float4 v = make_float4(0.f, 0.f, 0.f, 0.f);
        if (gr < NN) v = *(const float4*)(A2 + (size_t)gr * F + c4);
        sA[r][128 + c4 + 0] = v.x;
        sA[r][128 + c4 + 1] = v.y;
        sA[r][128 + c4 + 2] = v.z;
        sA[r][128 + c4 + 3] = v.w;
    }
    __syncthreads();

    int tr = tid >> 5;          // 0..7 -> rows tr*4 .. tr*4+3
    int tc = (tid & 31) << 2;   // cols tc .. tc+3
    float acc[4][4] = {};

#pragma unroll 4
    for (int k = 0; k < 256; ++k) {
        const float* Wrow = (k < 128) ? (WA + (size_t)k * F)
                                      : (WB + (size_t)(k - 128) * F);
        float4 w = *(const float4*)(Wrow + tc);
        float a0 = sA[tr * 4 + 0][k];
        float a1 = sA[tr * 4 + 1][k];
        float a2 = sA[tr * 4 + 2][k];
        float a3 = sA[tr * 4 + 3][k];
        acc[0][0] += a0 * w.x; acc[0][1] += a0 * w.y; acc[0][2] += a0 * w.z; acc[0][3] += a0 * w.w;
        acc[1][0] += a1 * w.x; acc[1][1] += a1 * w.y; acc[1][2] += a1 * w.z; acc[1][3] += a1 * w.w;
        acc[2][0] += a2 * w.x; acc[2][1] += a2 * w.y; acc[2][2] += a2 * w.z; acc[2][3] += a2 * w.w;
        acc[3][0] += a3 * w.x; acc[3][1] += a3 * w.y; acc[3][2] += a3 * w.z; acc[3][3] += a3 * w.w;
    }

    float4 b = *(const float4*)(bias + tc);
#pragma unroll
    for (int i = 0; i < 4; ++i) {
        int gr = row0 + tr * 4 + i;
        if (gr >= NN) continue;
        float4 o;
        o.x = acc[i][0] + b.x;
        o.y = acc[i][1] + b.y;
        o.z = acc[i][2] + b.z;
        o.w = acc[i][3] + b.w;
        if (relu) {
            o.x = fmaxf(o.x, 0.f); o.y = fmaxf(o.y, 0.f);
            o.z = fmaxf(o.z, 0.f); o.w = fmaxf(o.w, 0.f);
        }
        *(float4*)(C + (size_t)gr * F + tc) = o;
    }
}

// ---------------------------------------------------------------------------
// C1 = A @ W1, C2 = A @ W2  (K=128, no bias/act) -> Gs, Gd precompute
// ---------------------------------------------------------------------------
__launch_bounds__(256)
__global__ void k_gemm_dual(const float* __restrict__ A,
                            const float* __restrict__ W1, const float* __restrict__ W2,
                            float* __restrict__ C1, float* __restrict__ C2) {
    __shared__ float sA[32][128];
    int row0 = blockIdx.x * 32;
    int tid = threadIdx.x;

    for (int i = tid; i < 32 * 32; i += 256) {
        int r = i >> 5, c4 = (i & 31) << 2;
        int gr = row0 + r;
        float4 v = make_float4(0.f, 0.f, 0.f, 0.f);
        if (gr < NN) v = *(const float4*)(A + (size_t)gr * F + c4);
        sA[r][c4 + 0] = v.x;
        sA[r][c4 + 1] = v.y;
        sA[r][c4 + 2] = v.z;
        sA[r][c4 + 3] = v.w;
    }
    __syncthreads();

    int tr = tid >> 5;
    int tc = (tid & 31) << 2;
    float acc1[4][4] = {};
    float acc2[4][4] = {};

#pragma unroll 4
    for (int k = 0; k < 128; ++k) {
        float4 w1 = *(const float4*)(W1 + (size_t)k * F + tc);
        float4 w2 = *(const float4*)(W2 + (size_t)k * F + tc);
        float a0 = sA[tr * 4 + 0][k];
        float a1 = sA[tr * 4 + 1][k];
        float a2 = sA[tr * 4 + 2][k];
        float a3 = sA[tr * 4 + 3][k];
        acc1[0][0] += a0 * w1.x; acc1[0][1] += a0 * w1.y; acc1[0][2] += a0 * w1.z; acc1[0][3] += a0 * w1.w;
        acc1[1][0] += a1 * w1.x; acc1[1][1] += a1 * w1.y; acc1[1][2] += a1 * w1.z; acc1[1][3] += a1 * w1.w;
        acc1[2][0] += a2 * w1.x; acc1[2][1] += a2 * w1.y; acc1[2][2] += a2 * w1.z; acc1[2][3] += a2 * w1.w;
        acc1[3][0] += a3 * w1.x; acc1[3][1] += a3 * w1.y; acc1[3][2] += a3 * w1.z; acc1[3][3] += a3 * w1.w;
        acc2[0][0] += a0 * w2.x; acc2[0][1] += a0 * w2.y; acc2[0][2] += a0 * w2.z; acc2[0][3] += a0 * w2.w;
        acc2[1][0] += a1 * w2.x; acc2[1][1] += a1 * w2.y; acc2[1][2] += a1 * w2.z; acc2[1][3] += a1 * w2.w;
        acc2[2][0] += a2 * w2.x; acc2[2][1] += a2 * w2.y; acc2[2][2] += a2 * w2.z; acc2[2][3] += a2 * w2.w;
        acc2[3][0] += a3 * w2.x; acc2[3][1] += a3 * w2.y; acc2[3][2] += a3 * w2.z; acc2[3][3] += a3 * w2.w;
    }

#pragma unroll
    for (int i = 0; i < 4; ++i) {
        int gr = row0 + tr * 4 + i;
        if (gr >= NN) continue;
        float4 o1 = make_float4(acc1[i][0], acc1[i][1], acc1[i][2], acc1[i][3]);
        float4 o2 = make_float4(acc2[i][0], acc2[i][1], acc2[i][2], acc2[i][3]);
        *(float4*)(C1 + (size_t)gr * F + tc) = o1;
        *(float4*)(C2 + (size_t)gr * F + tc) = o2;
    }
}

// ---------------------------------------------------------------------------
// edge classifier: 32 threads per edge, float4 per lane.
// out[e] = relu(Gs[src]+Gd[dst]+ea@Wc1e+bc1) . Wc2 + bc2
// ---------------------------------------------------------------------------
__launch_bounds__(256)
__global__ void k_edge(const float* __restrict__ Gs, const float* __restrict__ Gd,
                       const float* __restrict__ ea, const int* __restrict__ src,
                       const int* __restrict__ dst, const float* __restrict__ Wc1e,
                       const float* __restrict__ bc1, const float* __restrict__ Wc2,
                       const float* __restrict__ bc2, float* __restrict__ out) {
    int gt = blockIdx.x * blockDim.x + threadIdx.x;
    int e = gt >> 5;
    if (e >= NE) return;
    int lane = threadIdx.x & 31;
    int c = lane << 2;
    int s = src[e], d = dst[e];

    float4 gs = *(const float4*)(Gs + (size_t)s * F + c);
    float4 gd = *(const float4*)(Gd + (size_t)d * F + c);
    float e0 = ea[(size_t)e * 3 + 0];
    float e1 = ea[(size_t)e * 3 + 1];
    float e2 = ea[(size_t)e * 3 + 2];
    float4 w0 = *(const float4*)(Wc1e + 0 * F + c);
    float4 w1 = *(const float4*)(Wc1e + 1 * F + c);
    float4 w2 = *(const float4*)(Wc1e + 2 * F + c);
    float4 b  = *(const float4*)(bc1 + c);

    float4 h;
    h.x = fmaxf(gs.x + gd.x + e0 * w0.x + e1 * w1.x + e2 * w2.x + b.x, 0.f);
    h.y = fmaxf(gs.y + gd.y + e0 * w0.y + e1 * w1.y + e2 * w2.y + b.y, 0.f);
    h.z = fmaxf(gs.z + gd.z + e0 * w0.z + e1 * w1.z + e2 * w2.z + b.z, 0.f);
    h.w = fmaxf(gs.w + gd.w + e0 * w0.w + e1 * w1.w + e2 * w2.w + b.w, 0.f);

    float4 wc = *(const float4*)(Wc2 + c);
    float p = h.x * wc.x + h.y * wc.y + h.z * wc.z + h.w * wc.w;
#pragma unroll
    for (int off = 16; off > 0; off >>= 1) p += __shfl_down(p, off, 32);
    if (lane == 0) out[e] = p + bc2[0];
}

// ---------------------------------------------------------------------------
extern "C" void kernel_launch(void* const* d_in, const int* in_sizes, int n_in,
                              void* d_out, int out_size, void* d_ws, size_t ws_size,
                              hipStream_t stream) {
    const float* x    = (const float*)d_in[0];
    const void*  ei   = d_in[1];
    const float* ea   = (const float*)d_in[2];
    const float* W1l  = (const float*)d_in[3];
    const float* b1l  = (const float*)d_in[4];
    const float* W1r  = (const float*)d_in[5];
    const float* W2l  = (const float*)d_in[6];
    const float* b2l  = (const float*)d_in[7];
    const float* W2r  = (const float*)d_in[8];
    const float* Wc1  = (const float*)d_in[9];
    const float* bc1  = (const float*)d_in[10];
    const float* Wc2  = (const float*)d_in[11];
    const float* bc2  = (const float*)d_in[12];
    float* out = (float*)d_out;

    char* w = (char*)d_ws;
    int* flag   = (int*)w;          w += 256;
    int* bsum   = (int*)w;          w += 1024;          // NBLK ints (<=256)
    int* boff   = (int*)w;          w += 1024;
    int* src    = (int*)w;          w += (size_t)NE * 4;
    int* dst    = (int*)w;          w += (size_t)NE * 4;
    int* ssort  = (int*)w;          w += (size_t)NE * 4;
    int* cnt    = (int*)w;          w += (size_t)NN * 4;
    float* inv  = (float*)w;        w += (size_t)NN * 4;
    int* rowptr = (int*)w;          w += (size_t)(NN + 1) * 4;
    int* fill   = (int*)w;          w += (size_t)NN * 4;
    w = (char*)(((size_t)w + 255) & ~(size_t)255);
    float* B0 = (float*)w;          w += (size_t)NN * F * 4;  // agg1, agg2, Gs
    float* B1 = (float*)w;          w += (size_t)NN * F * 4;  // h1, Gd
    float* B2 = (float*)w;          w += (size_t)NN * F * 4;  // h2

    hipMemsetAsync(flag, 0, 4, stream);
    hipMemsetAsync(cnt, 0, (size_t)NN * 4, stream);

    // edge-index normalization + degree histogram
    k_detect<<<(NE + 255) / 256, 256, 0, stream>>>((const unsigned int*)ei, flag);
    k_convert<<<(NE + 255) / 256, 256, 0, stream>>>(ei, flag, src, dst, cnt);
    k_inv<<<(NN + 255) / 256, 256, 0, stream>>>(cnt, inv);

    // CSR build: scan degrees -> rowptr, then counting-sort src by dst
    k_bsum<<<NBLK, 256, 0, stream>>>(cnt, bsum);
    k_bscan<<<1, 1, 0, stream>>>(bsum, boff);
    k_scan2<<<NBLK, 256, 0, stream>>>(cnt, boff, rowptr, fill);
    k_perm<<<(NE + 255) / 256, 256, 0, stream>>>(src, dst, fill, ssort);

    int gblocks = (NN + 31) / 32;
    int agblocks = (NN + 7) / 8;

    // conv1
    k_gather<<<agblocks, 256, 0, stream>>>(x, rowptr, ssort, B0);
    k_gemm_conv<<<gblocks, 256, 0, stream>>>(B0, inv, x, W1l, W1r, b1l, B1, 1);

    // conv2
    k_gather<<<agblocks, 256, 0, stream>>>(B1, rowptr, ssort, B0);
    k_gemm_conv<<<gblocks, 256, 0, stream>>>(B0, inv, B1, W2l, W2r, b2l, B2, 0);

    // classifier node-side precompute: Gs = h2 @ Wc1[0:128], Gd = h2 @ Wc1[128:256]
    k_gemm_dual<<<gblocks, 256, 0, stream>>>(B2, Wc1, Wc1 + 128 * F, B0, B1);

    // edge pass: 32 threads per edge
    k_edge<<<(int)(((size_t)NE * 32 + 255) / 256), 256, 0, stream>>>(
        B0, B1, ea, src, dst, Wc1 + 256 * F, bc1, Wc2, bc2, out);
}

// Round 3
// 646.477 us; speedup vs baseline: 5.3189x; 1.2271x over previous
//
#include <hip/hip_runtime.h>

#define NN 50000
#define NE 800000
#define F 128
#define NBLK ((NN + 255) / 256)   // 196 scan blocks

// ---------------------------------------------------------------------------
// dtype probe (sampled): check 256 odd 32-bit words. int64 layout -> all are
// zero high-halves (deterministic). int32 layout -> random node ids, P(all
// zero) = (1/50000)^256 ~ 0. One block only — avoids the 800k-atomic storm
// that cost 144 us in R2.
// ---------------------------------------------------------------------------
__global__ void k_detect(const unsigned int* __restrict__ w, int* __restrict__ nz) {
    __shared__ int s;
    if (threadIdx.x == 0) s = 0;
    __syncthreads();
    if (w[2 * threadIdx.x + 1] != 0u) atomicAdd(&s, 1);
    __syncthreads();
    if (threadIdx.x == 0) *nz = s;
}

// normalize edge_index -> int32 src/dst, and histogram in-degree (cnt[dst]++)
__global__ void k_convert(const void* __restrict__ ei, const int* __restrict__ nz,
                          int* __restrict__ src, int* __restrict__ dst,
                          int* __restrict__ cnt) {
    int e = blockIdx.x * blockDim.x + threadIdx.x;
    if (e >= NE) return;
    int s, d;
    if (*nz == 0) {  // int64 layout
        const long long* p = (const long long*)ei;
        s = (int)p[e];
        d = (int)p[NE + e];
    } else {         // int32 layout
        const int* p = (const int*)ei;
        s = p[e];
        d = p[NE + e];
    }
    src[e] = s;
    dst[e] = d;
    atomicAdd(&cnt[d], 1);
}

// ---- exclusive scan of cnt[NN] -> rowptr[NN+1], plus a working copy fill[]
__global__ void k_bsum(const int* __restrict__ cnt, int* __restrict__ bsum) {
    __shared__ int s[256];
    int i = blockIdx.x * 256 + threadIdx.x;
    s[threadIdx.x] = (i < NN) ? cnt[i] : 0;
    __syncthreads();
    for (int st = 128; st > 0; st >>= 1) {
        if (threadIdx.x < st) s[threadIdx.x] += s[threadIdx.x + st];
        __syncthreads();
    }
    if (threadIdx.x == 0) bsum[blockIdx.x] = s[0];
}

__global__ void k_bscan(const int* __restrict__ bsum, int* __restrict__ boff) {
    int acc = 0;
    for (int b = 0; b < NBLK; ++b) { boff[b] = acc; acc += bsum[b]; }
}

__global__ void k_scan2(const int* __restrict__ cnt, const int* __restrict__ boff,
                        int* __restrict__ rowptr, int* __restrict__ fill) {
    __shared__ int s[256];
    int i = blockIdx.x * 256 + threadIdx.x;
    int v = (i < NN) ? cnt[i] : 0;
    s[threadIdx.x] = v;
    __syncthreads();
    for (int st = 1; st < 256; st <<= 1) {
        int t = (threadIdx.x >= st) ? s[threadIdx.x - st] : 0;
        __syncthreads();
        s[threadIdx.x] += t;
        __syncthreads();
    }
    int excl = s[threadIdx.x] - v + boff[blockIdx.x];
    if (i < NN) { rowptr[i] = excl; fill[i] = excl; }
    if (i == NN - 1) rowptr[NN] = excl + v;
}

// counting-sort edges by dst: ssort[pos] = src[e]
__global__ void k_perm(const int* __restrict__ src, const int* __restrict__ dst,
                       int* __restrict__ fill, int* __restrict__ ssort) {
    int e = blockIdx.x * 256 + threadIdx.x;
    if (e >= NE) return;
    int pos = atomicAdd(&fill[dst[e]], 1);
    ssort[pos] = src[e];
}

// gather-reduce + mean: agg[n] = mean over in-neighbors of xin[src]
// 32 threads/node, float4 per lane. Degree comes free from rowptr.
__launch_bounds__(256)
__global__ void k_gather(const float* __restrict__ xin, const int* __restrict__ rowptr,
                         const int* __restrict__ ssort, float* __restrict__ agg) {
    int n = blockIdx.x * 8 + (threadIdx.x >> 5);
    if (n >= NN) return;
    int c = (threadIdx.x & 31) << 2;
    int beg = rowptr[n], end = rowptr[n + 1];
    float4 acc = make_float4(0.f, 0.f, 0.f, 0.f);
    for (int j = beg; j < end; ++j) {
        int s = ssort[j];
        float4 v = *(const float4*)(xin + (size_t)s * F + c);
        acc.x += v.x; acc.y += v.y; acc.z += v.z; acc.w += v.w;
    }
    float sc = 1.0f / (float)max(end - beg, 1);
    acc.x *= sc; acc.y *= sc; acc.z *= sc; acc.w *= sc;
    *(float4*)(agg + (size_t)n * F + c) = acc;
}

// ---------------------------------------------------------------------------
// C[r][:] = act( A1[r] @ WA + A2[r] @ WB + bias )   (K=128 each)
// fp32 vector GEMM, 32-row tile per block, each thread: 4 rows x 4 cols.
// ---------------------------------------------------------------------------
__launch_bounds__(256)
__global__ void k_gemm_conv(const float* __restrict__ A1, const float* __restrict__ A2,
                            const float* __restrict__ WA, const float* __restrict__ WB,
                            const float* __restrict__ bias, float* __restrict__ C,
                            int relu) {
    __shared__ float sA[32][256];  // [row][k]: k<128 = A1, k>=128 = A2
    int row0 = blockIdx.x * 32;
    int tid = threadIdx.x;

    for (int i = tid; i < 32 * 32; i += 256) {
        int r = i >> 5, c4 = (i & 31) << 2;
        int gr = row0 + r;
        float4 v = make_float4(0.f, 0.f, 0.f, 0.f);
        if (gr < NN) v = *(const float4*)(A1 + (size_t)gr * F + c4);
        sA[r][c4 + 0] = v.x;
        sA[r][c4 + 1] = v.y;
        sA[r][c4 + 2] = v.z;
        sA[r][c4 + 3] = v.w;
    }
    for (int i = tid; i < 32 * 32; i += 256) {
        int r = i >> 5, c4 = (i & 31) << 2;
        int gr = row0 + r;
        float4 v = make_float4(0.f, 0.f, 0.f, 0.f);
        if (gr < NN) v = *(const float4*)(A2 + (size_t)gr * F + c4);
        sA[r][128 + c4 + 0] = v.x;
        sA[r][128 + c4 + 1] = v.y;
        sA[r][128 + c4 + 2] = v.z;
        sA[r][128 + c4 + 3] = v.w;
    }
    __syncthreads();

    int tr = tid >> 5;          // 0..7 -> rows tr*4 .. tr*4+3
    int tc = (tid & 31) << 2;   // cols tc .. tc+3
    float acc[4][4] = {};

#pragma unroll 4
    for (int k = 0; k < 128; ++k) {
        float4 w = *(const float4*)(WA + (size_t)k * F + tc);
        float a0 = sA[tr * 4 + 0][k];
        float a1 = sA[tr * 4 + 1][k];
        float a2 = sA[tr * 4 + 2][k];
        float a3 = sA[tr * 4 + 3][k];
        acc[0][0] += a0 * w.x; acc[0][1] += a0 * w.y; acc[0][2] += a0 * w.z; acc[0][3] += a0 * w.w;
        acc[1][0] += a1 * w.x; acc[1][1] += a1 * w.y; acc[1][2] += a1 * w.z; acc[1][3] += a1 * w.w;
        acc[2][0] += a2 * w.x; acc[2][1] += a2 * w.y; acc[2][2] += a2 * w.z; acc[2][3] += a2 * w.w;
        acc[3][0] += a3 * w.x; acc[3][1] += a3 * w.y; acc[3][2] += a3 * w.z; acc[3][3] += a3 * w.w;
    }
#pragma unroll 4
    for (int k = 0; k < 128; ++k) {
        float4 w = *(const float4*)(WB + (size_t)k * F + tc);
        float a0 = sA[tr * 4 + 0][128 + k];
        float a1 = sA[tr * 4 + 1][128 + k];
        float a2 = sA[tr * 4 + 2][128 + k];
        float a3 = sA[tr * 4 + 3][128 + k];
        acc[0][0] += a0 * w.x; acc[0][1] += a0 * w.y; acc[0][2] += a0 * w.z; acc[0][3] += a0 * w.w;
        acc[1][0] += a1 * w.x; acc[1][1] += a1 * w.y; acc[1][2] += a1 * w.z; acc[1][3] += a1 * w.w;
        acc[2][0] += a2 * w.x; acc[2][1] += a2 * w.y; acc[2][2] += a2 * w.z; acc[2][3] += a2 * w.w;
        acc[3][0] += a3 * w.x; acc[3][1] += a3 * w.y; acc[3][2] += a3 * w.z; acc[3][3] += a3 * w.w;
    }

    float4 b = *(const float4*)(bias + tc);
#pragma unroll
    for (int i = 0; i < 4; ++i) {
        int gr = row0 + tr * 4 + i;
        if (gr >= NN) continue;
        float4 o;
        o.x = acc[i][0] + b.x;
        o.y = acc[i][1] + b.y;
        o.z = acc[i][2] + b.z;
        o.w = acc[i][3] + b.w;
        if (relu) {
            o.x = fmaxf(o.x, 0.f); o.y = fmaxf(o.y, 0.f);
            o.z = fmaxf(o.z, 0.f); o.w = fmaxf(o.w, 0.f);
        }
        *(float4*)(C + (size_t)gr * F + tc) = o;
    }
}

// ---------------------------------------------------------------------------
// C1 = A @ W1, C2 = A @ W2  (K=128, no bias/act) -> Gs, Gd precompute
// ---------------------------------------------------------------------------
__launch_bounds__(256)
__global__ void k_gemm_dual(const float* __restrict__ A,
                            const float* __restrict__ W1, const float* __restrict__ W2,
                            float* __restrict__ C1, float* __restrict__ C2) {
    __shared__ float sA[32][128];
    int row0 = blockIdx.x * 32;
    int tid = threadIdx.x;

    for (int i = tid; i < 32 * 32; i += 256) {
        int r = i >> 5, c4 = (i & 31) << 2;
        int gr = row0 + r;
        float4 v = make_float4(0.f, 0.f, 0.f, 0.f);
        if (gr < NN) v = *(const float4*)(A + (size_t)gr * F + c4);
        sA[r][c4 + 0] = v.x;
        sA[r][c4 + 1] = v.y;
        sA[r][c4 + 2] = v.z;
        sA[r][c4 + 3] = v.w;
    }
    __syncthreads();

    int tr = tid >> 5;
    int tc = (tid & 31) << 2;
    float acc1[4][4] = {};
    float acc2[4][4] = {};

#pragma unroll 4
    for (int k = 0; k < 128; ++k) {
        float4 w1 = *(const float4*)(W1 + (size_t)k * F + tc);
        float4 w2 = *(const float4*)(W2 + (size_t)k * F + tc);
        float a0 = sA[tr * 4 + 0][k];
        float a1 = sA[tr * 4 + 1][k];
        float a2 = sA[tr * 4 + 2][k];
        float a3 = sA[tr * 4 + 3][k];
        acc1[0][0] += a0 * w1.x; acc1[0][1] += a0 * w1.y; acc1[0][2] += a0 * w1.z; acc1[0][3] += a0 * w1.w;
        acc1[1][0] += a1 * w1.x; acc1[1][1] += a1 * w1.y; acc1[1][2] += a1 * w1.z; acc1[1][3] += a1 * w1.w;
        acc1[2][0] += a2 * w1.x; acc1[2][1] += a2 * w1.y; acc1[2][2] += a2 * w1.z; acc1[2][3] += a2 * w1.w;
        acc1[3][0] += a3 * w1.x; acc1[3][1] += a3 * w1.y; acc1[3][2] += a3 * w1.z; acc1[3][3] += a3 * w1.w;
        acc2[0][0] += a0 * w2.x; acc2[0][1] += a0 * w2.y; acc2[0][2] += a0 * w2.z; acc2[0][3] += a0 * w2.w;
        acc2[1][0] += a1 * w2.x; acc2[1][1] += a1 * w2.y; acc2[1][2] += a1 * w2.z; acc2[1][3] += a1 * w2.w;
        acc2[2][0] += a2 * w2.x; acc2[2][1] += a2 * w2.y; acc2[2][2] += a2 * w2.z; acc2[2][3] += a2 * w2.w;
        acc2[3][0] += a3 * w2.x; acc2[3][1] += a3 * w2.y; acc2[3][2] += a3 * w2.z; acc2[3][3] += a3 * w2.w;
    }

#pragma unroll
    for (int i = 0; i < 4; ++i) {
        int gr = row0 + tr * 4 + i;
        if (gr >= NN) continue;
        float4 o1 = make_float4(acc1[i][0], acc1[i][1], acc1[i][2], acc1[i][3]);
        float4 o2 = make_float4(acc2[i][0], acc2[i][1], acc2[i][2], acc2[i][3]);
        *(float4*)(C1 + (size_t)gr * F + tc) = o1;
        *(float4*)(C2 + (size_t)gr * F + tc) = o2;
    }
}

// ---------------------------------------------------------------------------
// edge classifier: grid-stride, 32 threads per edge. Weight/bias fragments
// are edge-invariant per lane -> hoisted into registers outside the loop.
// out[e] = relu(Gs[src]+Gd[dst]+ea@Wc1e+bc1) . Wc2 + bc2
// ---------------------------------------------------------------------------
__launch_bounds__(256)
__global__ void k_edge(const float* __restrict__ Gs, const float* __restrict__ Gd,
                       const float* __restrict__ ea, const int* __restrict__ src,
                       const int* __restrict__ dst, const float* __restrict__ Wc1e,
                       const float* __restrict__ bc1, const float* __restrict__ Wc2,
                       const float* __restrict__ bc2, float* __restrict__ out) {
    int lane = threadIdx.x & 31;
    int c = lane << 2;
    float4 w0 = *(const float4*)(Wc1e + 0 * F + c);
    float4 w1 = *(const float4*)(Wc1e + 1 * F + c);
    float4 w2 = *(const float4*)(Wc1e + 2 * F + c);
    float4 b  = *(const float4*)(bc1 + c);
    float4 wc = *(const float4*)(Wc2 + c);
    float bb  = bc2[0];

    int grp = (blockIdx.x * blockDim.x + threadIdx.x) >> 5;
    int ngrp = (gridDim.x * blockDim.x) >> 5;

    for (int e = grp; e < NE; e += ngrp) {
        int s = src[e], d = dst[e];
        float4 gs = *(const float4*)(Gs + (size_t)s * F + c);
        float4 gd = *(const float4*)(Gd + (size_t)d * F + c);
        float e0 = ea[(size_t)e * 3 + 0];
        float e1 = ea[(size_t)e * 3 + 1];
        float e2 = ea[(size_t)e * 3 + 2];

        float4 h;
        h.x = fmaxf(gs.x + gd.x + e0 * w0.x + e1 * w1.x + e2 * w2.x + b.x, 0.f);
        h.y = fmaxf(gs.y + gd.y + e0 * w0.y + e1 * w1.y + e2 * w2.y + b.y, 0.f);
        h.z = fmaxf(gs.z + gd.z + e0 * w0.z + e1 * w1.z + e2 * w2.z + b.z, 0.f);
        h.w = fmaxf(gs.w + gd.w + e0 * w0.w + e1 * w1.w + e2 * w2.w + b.w, 0.f);

        float p = h.x * wc.x + h.y * wc.y + h.z * wc.z + h.w * wc.w;
#pragma unroll
        for (int off = 16; off > 0; off >>= 1) p += __shfl_down(p, off, 32);
        if (lane == 0) out[e] = p + bb;
    }
}

// ---------------------------------------------------------------------------
extern "C" void kernel_launch(void* const* d_in, const int* in_sizes, int n_in,
                              void* d_out, int out_size, void* d_ws, size_t ws_size,
                              hipStream_t stream) {
    const float* x    = (const float*)d_in[0];
    const void*  ei   = d_in[1];
    const float* ea   = (const float*)d_in[2];
    const float* W1l  = (const float*)d_in[3];
    const float* b1l  = (const float*)d_in[4];
    const float* W1r  = (const float*)d_in[5];
    const float* W2l  = (const float*)d_in[6];
    const float* b2l  = (const float*)d_in[7];
    const float* W2r  = (const float*)d_in[8];
    const float* Wc1  = (const float*)d_in[9];
    const float* bc1  = (const float*)d_in[10];
    const float* Wc2  = (const float*)d_in[11];
    const float* bc2  = (const float*)d_in[12];
    float* out = (float*)d_out;

    char* w = (char*)d_ws;
    int* flag   = (int*)w;          w += 256;
    int* bsum   = (int*)w;          w += 1024;          // NBLK ints (<=256)
    int* boff   = (int*)w;          w += 1024;
    int* src    = (int*)w;          w += (size_t)NE * 4;
    int* dst    = (int*)w;          w += (size_t)NE * 4;
    int* ssort  = (int*)w;          w += (size_t)NE * 4;
    int* cnt    = (int*)w;          w += (size_t)NN * 4;
    int* rowptr = (int*)w;          w += (size_t)(NN + 1) * 4;
    int* fill   = (int*)w;          w += (size_t)NN * 4;
    w = (char*)(((size_t)w + 255) & ~(size_t)255);
    float* B0 = (float*)w;          w += (size_t)NN * F * 4;  // agg1, agg2, Gs
    float* B1 = (float*)w;          w += (size_t)NN * F * 4;  // h1, Gd
    float* B2 = (float*)w;          w += (size_t)NN * F * 4;  // h2

    hipMemsetAsync(cnt, 0, (size_t)NN * 4, stream);

    // edge-index normalization + degree histogram
    k_detect<<<1, 256, 0, stream>>>((const unsigned int*)ei, flag);
    k_convert<<<(NE + 255) / 256, 256, 0, stream>>>(ei, flag, src, dst, cnt);

    // CSR build: scan degrees -> rowptr, then counting-sort src by dst
    k_bsum<<<NBLK, 256, 0, stream>>>(cnt, bsum);
    k_bscan<<<1, 1, 0, stream>>>(bsum, boff);
    k_scan2<<<NBLK, 256, 0, stream>>>(cnt, boff, rowptr, fill);
    k_perm<<<(NE + 255) / 256, 256, 0, stream>>>(src, dst, fill, ssort);

    int gblocks = (NN + 31) / 32;
    int agblocks = (NN + 7) / 8;

    // conv1
    k_gather<<<agblocks, 256, 0, stream>>>(x, rowptr, ssort, B0);
    k_gemm_conv<<<gblocks, 256, 0, stream>>>(B0, x, W1l, W1r, b1l, B1, 1);

    // conv2
    k_gather<<<agblocks, 256, 0, stream>>>(B1, rowptr, ssort, B0);
    k_gemm_conv<<<gblocks, 256, 0, stream>>>(B0, B1, W2l, W2r, b2l, B2, 0);

    // classifier node-side precompute: Gs = h2 @ Wc1[0:128], Gd = h2 @ Wc1[128:256]
    k_gemm_dual<<<gblocks, 256, 0, stream>>>(B2, Wc1, Wc1 + 128 * F, B0, B1);

    // edge pass: grid-stride, 32 threads per edge
    k_edge<<<4096, 256, 0, stream>>>(B0, B1, ea, src, dst,
                                     Wc1 + 256 * F, bc1, Wc2, bc2, out);
}

// Round 4
// 535.112 us; speedup vs baseline: 6.4258x; 1.2081x over previous
//
#include <hip/hip_runtime.h>

#define NN 50000
#define NE 800000
#define F 128
#define NBLK ((NN + 255) / 256)   // 196 scan blocks

typedef __attribute__((ext_vector_type(4))) unsigned short ushort4_t;
typedef __attribute__((ext_vector_type(8))) unsigned short ushort8_t;

__device__ __forceinline__ float b2f(unsigned short u) {
    return __uint_as_float((unsigned int)u << 16);
}
__device__ __forceinline__ unsigned short f2b(float f) {
    unsigned int u = __float_as_uint(f);
    return (unsigned short)((u + 0x7fffu + ((u >> 16) & 1u)) >> 16);
}

// ---------------------------------------------------------------------------
// dtype probe (sampled): 256 odd words zero <=> int64 layout.
// ---------------------------------------------------------------------------
__global__ void k_detect(const unsigned int* __restrict__ w, int* __restrict__ nz) {
    __shared__ int s;
    if (threadIdx.x == 0) s = 0;
    __syncthreads();
    if (w[2 * threadIdx.x + 1] != 0u) atomicAdd(&s, 1);
    __syncthreads();
    if (threadIdx.x == 0) *nz = s;
}

// normalize edge_index -> int32 src/dst, and histogram in-degree (cnt[dst]++)
__global__ void k_convert(const void* __restrict__ ei, const int* __restrict__ nz,
                          int* __restrict__ src, int* __restrict__ dst,
                          int* __restrict__ cnt) {
    int e = blockIdx.x * blockDim.x + threadIdx.x;
    if (e >= NE) return;
    int s, d;
    if (*nz == 0) {
        const long long* p = (const long long*)ei;
        s = (int)p[e];
        d = (int)p[NE + e];
    } else {
        const int* p = (const int*)ei;
        s = p[e];
        d = p[NE + e];
    }
    src[e] = s;
    dst[e] = d;
    atomicAdd(&cnt[d], 1);
}

// fp32 -> bf16 cast, float4/ushort4 per thread
__global__ void k_cast(const float* __restrict__ in, unsigned short* __restrict__ out,
                       int n4) {
    int i = blockIdx.x * blockDim.x + threadIdx.x;
    if (i >= n4) return;
    float4 v = ((const float4*)in)[i];
    ushort4_t o;
    o.x = f2b(v.x); o.y = f2b(v.y); o.z = f2b(v.z); o.w = f2b(v.w);
    ((ushort4_t*)out)[i] = o;
}

// ---- exclusive scan of cnt[NN] -> rowptr[NN+1], plus working copy fill[]
__global__ void k_bsum(const int* __restrict__ cnt, int* __restrict__ bsum) {
    __shared__ int s[256];
    int i = blockIdx.x * 256 + threadIdx.x;
    s[threadIdx.x] = (i < NN) ? cnt[i] : 0;
    __syncthreads();
    for (int st = 128; st > 0; st >>= 1) {
        if (threadIdx.x < st) s[threadIdx.x] += s[threadIdx.x + st];
        __syncthreads();
    }
    if (threadIdx.x == 0) bsum[blockIdx.x] = s[0];
}

__global__ void k_bscan(const int* __restrict__ bsum, int* __restrict__ boff) {
    int acc = 0;
    for (int b = 0; b < NBLK; ++b) { boff[b] = acc; acc += bsum[b]; }
}

__global__ void k_scan2(const int* __restrict__ cnt, const int* __restrict__ boff,
                        int* __restrict__ rowptr, int* __restrict__ fill) {
    __shared__ int s[256];
    int i = blockIdx.x * 256 + threadIdx.x;
    int v = (i < NN) ? cnt[i] : 0;
    s[threadIdx.x] = v;
    __syncthreads();
    for (int st = 1; st < 256; st <<= 1) {
        int t = (threadIdx.x >= st) ? s[threadIdx.x - st] : 0;
        __syncthreads();
        s[threadIdx.x] += t;
        __syncthreads();
    }
    int excl = s[threadIdx.x] - v + boff[blockIdx.x];
    if (i < NN) { rowptr[i] = excl; fill[i] = excl; }
    if (i == NN - 1) rowptr[NN] = excl + v;
}

// counting-sort edges by dst: ssort[pos] = src[e]
__global__ void k_perm(const int* __restrict__ src, const int* __restrict__ dst,
                       int* __restrict__ fill, int* __restrict__ ssort) {
    int e = blockIdx.x * 256 + threadIdx.x;
    if (e >= NE) return;
    int pos = atomicAdd(&fill[dst[e]], 1);
    ssort[pos] = src[e];
}

// gather-reduce + mean over bf16 rows: 16 lanes/node, 8 ch/lane (16B loads)
__launch_bounds__(256)
__global__ void k_gather(const unsigned short* __restrict__ xin,
                         const int* __restrict__ rowptr,
                         const int* __restrict__ ssort, float* __restrict__ agg) {
    int n = blockIdx.x * 16 + (threadIdx.x >> 4);
    if (n >= NN) return;
    int c = (threadIdx.x & 15) << 3;
    int beg = rowptr[n], end = rowptr[n + 1];
    float acc[8] = {};
    for (int j = beg; j < end; ++j) {
        int s = ssort[j];
        ushort8_t v = *(const ushort8_t*)(xin + (size_t)s * F + c);
#pragma unroll
        for (int k = 0; k < 8; ++k) acc[k] += b2f(v[k]);
    }
    float sc = 1.0f / (float)max(end - beg, 1);
    float4 o0 = make_float4(acc[0] * sc, acc[1] * sc, acc[2] * sc, acc[3] * sc);
    float4 o1 = make_float4(acc[4] * sc, acc[5] * sc, acc[6] * sc, acc[7] * sc);
    *(float4*)(agg + (size_t)n * F + c) = o0;
    *(float4*)(agg + (size_t)n * F + c + 4) = o1;
}

// ---------------------------------------------------------------------------
// C = act( A1 @ WA + A2 @ WB + bias ); A1 fp32; A2 fp32 or bf16 (a2bf).
// Outputs: C fp32 (if non-null) and/or Ch bf16 (if non-null).
// ---------------------------------------------------------------------------
__launch_bounds__(256)
__global__ void k_gemm_conv(const float* __restrict__ A1, const void* __restrict__ A2,
                            int a2bf,
                            const float* __restrict__ WA, const float* __restrict__ WB,
                            const float* __restrict__ bias,
                            float* __restrict__ C, unsigned short* __restrict__ Ch,
                            int relu) {
    __shared__ float sA[32][256];  // [row][k]: k<128 = A1, k>=128 = A2
    int row0 = blockIdx.x * 32;
    int tid = threadIdx.x;

    for (int i = tid; i < 32 * 32; i += 256) {
        int r = i >> 5, c4 = (i & 31) << 2;
        int gr = row0 + r;
        float4 v = make_float4(0.f, 0.f, 0.f, 0.f);
        if (gr < NN) v = *(const float4*)(A1 + (size_t)gr * F + c4);
        sA[r][c4 + 0] = v.x;
        sA[r][c4 + 1] = v.y;
        sA[r][c4 + 2] = v.z;
        sA[r][c4 + 3] = v.w;
    }
    for (int i = tid; i < 32 * 32; i += 256) {
        int r = i >> 5, c4 = (i & 31) << 2;
        int gr = row0 + r;
        float4 v = make_float4(0.f, 0.f, 0.f, 0.f);
        if (gr < NN) {
            if (a2bf) {
                ushort4_t u = *(const ushort4_t*)((const unsigned short*)A2 +
                                                  (size_t)gr * F + c4);
                v = make_float4(b2f(u.x), b2f(u.y), b2f(u.z), b2f(u.w));
            } else {
                v = *(const float4*)((const float*)A2 + (size_t)gr * F + c4);
            }
        }
        sA[r][128 + c4 + 0] = v.x;
        sA[r][128 + c4 + 1] = v.y;
        sA[r][128 + c4 + 2] = v.z;
        sA[r][128 + c4 + 3] = v.w;
    }
    __syncthreads();

    int tr = tid >> 5;          // 0..7 -> rows tr*4 .. tr*4+3
    int tc = (tid & 31) << 2;   // cols tc .. tc+3
    float acc[4][4] = {};

#pragma unroll 4
    for (int k = 0; k < 128; ++k) {
        float4 w = *(const float4*)(WA + (size_t)k * F + tc);
        float a0 = sA[tr * 4 + 0][k];
        float a1 = sA[tr * 4 + 1][k];
        float a2 = sA[tr * 4 + 2][k];
        float a3 = sA[tr * 4 + 3][k];
        acc[0][0] += a0 * w.x; acc[0][1] += a0 * w.y; acc[0][2] += a0 * w.z; acc[0][3] += a0 * w.w;
        acc[1][0] += a1 * w.x; acc[1][1] += a1 * w.y; acc[1][2] += a1 * w.z; acc[1][3] += a1 * w.w;
        acc[2][0] += a2 * w.x; acc[2][1] += a2 * w.y; acc[2][2] += a2 * w.z; acc[2][3] += a2 * w.w;
        acc[3][0] += a3 * w.x; acc[3][1] += a3 * w.y; acc[3][2] += a3 * w.z; acc[3][3] += a3 * w.w;
    }
#pragma unroll 4
    for (int k = 0; k < 128; ++k) {
        float4 w = *(const float4*)(WB + (size_t)k * F + tc);
        float a0 = sA[tr * 4 + 0][128 + k];
        float a1 = sA[tr * 4 + 1][128 + k];
        float a2 = sA[tr * 4 + 2][128 + k];
        float a3 = sA[tr * 4 + 3][128 + k];
        acc[0][0] += a0 * w.x; acc[0][1] += a0 * w.y; acc[0][2] += a0 * w.z; acc[0][3] += a0 * w.w;
        acc[1][0] += a1 * w.x; acc[1][1] += a1 * w.y; acc[1][2] += a1 * w.z; acc[1][3] += a1 * w.w;
        acc[2][0] += a2 * w.x; acc[2][1] += a2 * w.y; acc[2][2] += a2 * w.z; acc[2][3] += a2 * w.w;
        acc[3][0] += a3 * w.x; acc[3][1] += a3 * w.y; acc[3][2] += a3 * w.z; acc[3][3] += a3 * w.w;
    }

    float4 b = *(const float4*)(bias + tc);
#pragma unroll
    for (int i = 0; i < 4; ++i) {
        int gr = row0 + tr * 4 + i;
        if (gr >= NN) continue;
        float4 o;
        o.x = acc[i][0] + b.x;
        o.y = acc[i][1] + b.y;
        o.z = acc[i][2] + b.z;
        o.w = acc[i][3] + b.w;
        if (relu) {
            o.x = fmaxf(o.x, 0.f); o.y = fmaxf(o.y, 0.f);
            o.z = fmaxf(o.z, 0.f); o.w = fmaxf(o.w, 0.f);
        }
        if (C) *(float4*)(C + (size_t)gr * F + tc) = o;
        if (Ch) {
            ushort4_t u;
            u.x = f2b(o.x); u.y = f2b(o.y); u.z = f2b(o.z); u.w = f2b(o.w);
            *(ushort4_t*)(Ch + (size_t)gr * F + tc) = u;
        }
    }
}

// ---------------------------------------------------------------------------
// C1 = A @ W1, C2 = A @ W2 (bf16 outputs) -> Gs, Gd precompute
// ---------------------------------------------------------------------------
__launch_bounds__(256)
__global__ void k_gemm_dual(const float* __restrict__ A,
                            const float* __restrict__ W1, const float* __restrict__ W2,
                            unsigned short* __restrict__ C1,
                            unsigned short* __restrict__ C2) {
    __shared__ float sA[32][128];
    int row0 = blockIdx.x * 32;
    int tid = threadIdx.x;

    for (int i = tid; i < 32 * 32; i += 256) {
        int r = i >> 5, c4 = (i & 31) << 2;
        int gr = row0 + r;
        float4 v = make_float4(0.f, 0.f, 0.f, 0.f);
        if (gr < NN) v = *(const float4*)(A + (size_t)gr * F + c4);
        sA[r][c4 + 0] = v.x;
        sA[r][c4 + 1] = v.y;
        sA[r][c4 + 2] = v.z;
        sA[r][c4 + 3] = v.w;
    }
    __syncthreads();

    int tr = tid >> 5;
    int tc = (tid & 31) << 2;
    float acc1[4][4] = {};
    float acc2[4][4] = {};

#pragma unroll 4
    for (int k = 0; k < 128; ++k) {
        float4 w1 = *(const float4*)(W1 + (size_t)k * F + tc);
        float4 w2 = *(const float4*)(W2 + (size_t)k * F + tc);
        float a0 = sA[tr * 4 + 0][k];
        float a1 = sA[tr * 4 + 1][k];
        float a2 = sA[tr * 4 + 2][k];
        float a3 = sA[tr * 4 + 3][k];
        acc1[0][0] += a0 * w1.x; acc1[0][1] += a0 * w1.y; acc1[0][2] += a0 * w1.z; acc1[0][3] += a0 * w1.w;
        acc1[1][0] += a1 * w1.x; acc1[1][1] += a1 * w1.y; acc1[1][2] += a1 * w1.z; acc1[1][3] += a1 * w1.w;
        acc1[2][0] += a2 * w1.x; acc1[2][1] += a2 * w1.y; acc1[2][2] += a2 * w1.z; acc1[2][3] += a2 * w1.w;
        acc1[3][0] += a3 * w1.x; acc1[3][1] += a3 * w1.y; acc1[3][2] += a3 * w1.z; acc1[3][3] += a3 * w1.w;
        acc2[0][0] += a0 * w2.x; acc2[0][1] += a0 * w2.y; acc2[0][2] += a0 * w2.z; acc2[0][3] += a0 * w2.w;
        acc2[1][0] += a1 * w2.x; acc2[1][1] += a1 * w2.y; acc2[1][2] += a1 * w2.z; acc2[1][3] += a1 * w2.w;
        acc2[2][0] += a2 * w2.x; acc2[2][1] += a2 * w2.y; acc2[2][2] += a2 * w2.z; acc2[2][3] += a2 * w2.w;
        acc2[3][0] += a3 * w2.x; acc2[3][1] += a3 * w2.y; acc2[3][2] += a3 * w2.z; acc2[3][3] += a3 * w2.w;
    }

#pragma unroll
    for (int i = 0; i < 4; ++i) {
        int gr = row0 + tr * 4 + i;
        if (gr >= NN) continue;
        ushort4_t u1, u2;
        u1.x = f2b(acc1[i][0]); u1.y = f2b(acc1[i][1]); u1.z = f2b(acc1[i][2]); u1.w = f2b(acc1[i][3]);
        u2.x = f2b(acc2[i][0]); u2.y = f2b(acc2[i][1]); u2.z = f2b(acc2[i][2]); u2.w = f2b(acc2[i][3]);
        *(ushort4_t*)(C1 + (size_t)gr * F + tc) = u1;
        *(ushort4_t*)(C2 + (size_t)gr * F + tc) = u2;
    }
}

// ---------------------------------------------------------------------------
// edge classifier: grid-stride, 16 lanes/edge, 8 ch/lane (16B bf16 loads).
// ---------------------------------------------------------------------------
__launch_bounds__(256)
__global__ void k_edge(const unsigned short* __restrict__ Gs,
                       const unsigned short* __restrict__ Gd,
                       const float* __restrict__ ea, const int* __restrict__ src,
                       const int* __restrict__ dst, const float* __restrict__ Wc1e,
                       const float* __restrict__ bc1, const float* __restrict__ Wc2,
                       const float* __restrict__ bc2, float* __restrict__ out) {
    int lane = threadIdx.x & 15;
    int c = lane << 3;
    float w0[8], w1[8], w2[8], bb[8], wc[8];
#pragma unroll
    for (int k = 0; k < 8; ++k) {
        w0[k] = Wc1e[0 * F + c + k];
        w1[k] = Wc1e[1 * F + c + k];
        w2[k] = Wc1e[2 * F + c + k];
        bb[k] = bc1[c + k];
        wc[k] = Wc2[c + k];
    }
    float bout = bc2[0];

    int grp = (blockIdx.x * blockDim.x + threadIdx.x) >> 4;
    int ngrp = (gridDim.x * blockDim.x) >> 4;

    for (int e = grp; e < NE; e += ngrp) {
        int s = src[e], d = dst[e];
        ushort8_t gs = *(const ushort8_t*)(Gs + (size_t)s * F + c);
        ushort8_t gd = *(const ushort8_t*)(Gd + (size_t)d * F + c);
        float e0 = ea[(size_t)e * 3 + 0];
        float e1 = ea[(size_t)e * 3 + 1];
        float e2 = ea[(size_t)e * 3 + 2];

        float p = 0.f;
#pragma unroll
        for (int k = 0; k < 8; ++k) {
            float h = b2f(gs[k]) + b2f(gd[k]) + e0 * w0[k] + e1 * w1[k] + e2 * w2[k] + bb[k];
            h = fmaxf(h, 0.f);
            p += h * wc[k];
        }
#pragma unroll
        for (int off = 8; off > 0; off >>= 1) p += __shfl_down(p, off, 16);
        if (lane == 0) out[e] = p + bout;
    }
}

// ---------------------------------------------------------------------------
extern "C" void kernel_launch(void* const* d_in, const int* in_sizes, int n_in,
                              void* d_out, int out_size, void* d_ws, size_t ws_size,
                              hipStream_t stream) {
    const float* x    = (const float*)d_in[0];
    const void*  ei   = d_in[1];
    const float* ea   = (const float*)d_in[2];
    const float* W1l  = (const float*)d_in[3];
    const float* b1l  = (const float*)d_in[4];
    const float* W1r  = (const float*)d_in[5];
    const float* W2l  = (const float*)d_in[6];
    const float* b2l  = (const float*)d_in[7];
    const float* W2r  = (const float*)d_in[8];
    const float* Wc1  = (const float*)d_in[9];
    const float* bc1  = (const float*)d_in[10];
    const float* Wc2  = (const float*)d_in[11];
    const float* bc2  = (const float*)d_in[12];
    float* out = (float*)d_out;

    char* w = (char*)d_ws;
    int* flag   = (int*)w;          w += 256;
    int* bsum   = (int*)w;          w += 1024;
    int* boff   = (int*)w;          w += 1024;
    int* src    = (int*)w;          w += (size_t)NE * 4;
    int* dst    = (int*)w;          w += (size_t)NE * 4;
    int* ssort  = (int*)w;          w += (size_t)NE * 4;
    int* cnt    = (int*)w;          w += (size_t)NN * 4;
    int* rowptr = (int*)w;          w += (size_t)(NN + 1) * 4;
    int* fill   = (int*)w;          w += (size_t)NN * 4;
    w = (char*)(((size_t)w + 255) & ~(size_t)255);
    float* B0 = (float*)w;              w += (size_t)NN * F * 4;  // agg1, agg2, h2
    unsigned short* xh  = (unsigned short*)w;  w += (size_t)NN * F * 2;
    unsigned short* h1h = (unsigned short*)w;  w += (size_t)NN * F * 2;
    unsigned short* Gsh = (unsigned short*)w;  w += (size_t)NN * F * 2;
    unsigned short* Gdh = (unsigned short*)w;  w += (size_t)NN * F * 2;

    hipMemsetAsync(cnt, 0, (size_t)NN * 4, stream);

    // edge-index normalization + degree histogram + bf16 feature cast
    k_detect<<<1, 256, 0, stream>>>((const unsigned int*)ei, flag);
    k_convert<<<(NE + 255) / 256, 256, 0, stream>>>(ei, flag, src, dst, cnt);
    k_cast<<<(NN * F / 4 + 255) / 256, 256, 0, stream>>>(x, xh, NN * F / 4);

    // CSR build
    k_bsum<<<NBLK, 256, 0, stream>>>(cnt, bsum);
    k_bscan<<<1, 1, 0, stream>>>(bsum, boff);
    k_scan2<<<NBLK, 256, 0, stream>>>(cnt, boff, rowptr, fill);
    k_perm<<<(NE + 255) / 256, 256, 0, stream>>>(src, dst, fill, ssort);

    int gblocks = (NN + 31) / 32;
    int agblocks = (NN + 15) / 16;

    // conv1: agg1 = mean-gather(xh); h1 (bf16) = relu(agg1@W1l + x@W1r + b1l)
    k_gather<<<agblocks, 256, 0, stream>>>(xh, rowptr, ssort, B0);
    k_gemm_conv<<<gblocks, 256, 0, stream>>>(B0, x, 0, W1l, W1r, b1l,
                                             nullptr, h1h, 1);

    // conv2: agg2 = mean-gather(h1h); h2 (fp32, aliases B0) = agg2@W2l + h1@W2r + b2l
    k_gather<<<agblocks, 256, 0, stream>>>(h1h, rowptr, ssort, B0);
    k_gemm_conv<<<gblocks, 256, 0, stream>>>(B0, h1h, 1, W2l, W2r, b2l,
                                             B0, nullptr, 0);

    // classifier node-side precompute: Gs/Gd (bf16) = h2 @ Wc1 halves
    k_gemm_dual<<<gblocks, 256, 0, stream>>>(B0, Wc1, Wc1 + 128 * F, Gsh, Gdh);

    // edge pass: 16 lanes per edge
    k_edge<<<4096, 256, 0, stream>>>(Gsh, Gdh, ea, src, dst,
                                     Wc1 + 256 * F, bc1, Wc2, bc2, out);
}